// Round 1
// baseline (1048.064 us; speedup 1.0000x reference)
//
#include <hip/hip_runtime.h>
#include <stdint.h>

#define EPSF 1e-5f
#define NEG_INF (-1e30f)

typedef float f32x4 __attribute__((ext_vector_type(4)));
typedef __bf16 bf16x8 __attribute__((ext_vector_type(8)));

typedef __attribute__((address_space(3))) unsigned char* as3_ptr;
typedef const __attribute__((address_space(1))) unsigned char* as1_ptr;

__device__ __forceinline__ void async16(const void* g, void* l) {
  __builtin_amdgcn_global_load_lds((as1_ptr)g, (as3_ptr)l, 16, 0, 0);
}

__device__ __forceinline__ unsigned short f2bf(float f) {
  union { float f; unsigned int u; } v; v.f = f;
  unsigned int r = v.u + 0x7FFFu + ((v.u >> 16) & 1u);
  return (unsigned short)(r >> 16);
}

// ---------------- T0: generic 32x32 transpose: dst[c][r] = src[r][c], src is R x C
__global__ __launch_bounds__(256) void transpose_k(const float* __restrict__ src,
                                                   float* __restrict__ dst, int R, int C) {
  __shared__ float tl[32][33];
  int tx = threadIdx.x & 31, ty = threadIdx.x >> 5;
  int c0 = blockIdx.x * 32, r0 = blockIdx.y * 32;
#pragma unroll
  for (int i = 0; i < 4; i++) {
    tl[ty + i * 8][tx] = src[(size_t)(r0 + ty + i * 8) * C + c0 + tx];
  }
  __syncthreads();
#pragma unroll
  for (int i = 0; i < 4; i++) {
    dst[(size_t)(c0 + ty + i * 8) * R + r0 + tx] = tl[tx][ty + i * 8];
  }
}

// ---------------- A1: QKV projection. xT is [a][t][c] (128 x 512 x 32).
// Q/K/V stored [a][r][t]: flat = a*16384 + r*512 + t, r = h*4+d.
__global__ __launch_bounds__(256) void qkv_k(const float* __restrict__ xT,
    const float* __restrict__ Wq, const float* __restrict__ bq,
    const float* __restrict__ Wk, const float* __restrict__ bk,
    const float* __restrict__ Wv, const float* __restrict__ bv,
    float* __restrict__ Q, float* __restrict__ Kq, float* __restrict__ Vq) {
  __shared__ float xs[64 * 33];
  __shared__ float wq[32 * 33], wk[32 * 33], wvs[32 * 33];
  __shared__ float bqs[32], bks[32], bvs[32];
  int tid = threadIdx.x;
  int a = blockIdx.x;
  int tbase = blockIdx.y * 256;
#pragma unroll
  for (int i = 0; i < 4; i++) {
    int e = i * 256 + tid; int r = e >> 5, c = e & 31;
    wq[r * 33 + c] = Wq[e]; wk[r * 33 + c] = Wk[e]; wvs[r * 33 + c] = Wv[e];
  }
  if (tid < 32) { bqs[tid] = bq[tid]; bks[tid] = bk[tid]; bvs[tid] = bv[tid]; }
  int tl = tid & 63, rg = tid >> 6;
  for (int ch = 0; ch < 4; ch++) {
    __syncthreads();
#pragma unroll
    for (int i = 0; i < 8; i++) {
      int e = i * 256 + tid; int r = e >> 5, c = e & 31;
      xs[r * 33 + c] = xT[(size_t)a * 16384 + (size_t)(tbase + ch * 64) * 32 + e];
    }
    __syncthreads();
    float qa[8], ka[8], va[8];
#pragma unroll
    for (int r8 = 0; r8 < 8; r8++) {
      int r = rg * 8 + r8; qa[r8] = bqs[r]; ka[r8] = bks[r]; va[r8] = bvs[r];
    }
    for (int c = 0; c < 32; c++) {
      float xv = xs[tl * 33 + c];
#pragma unroll
      for (int r8 = 0; r8 < 8; r8++) {
        int r = rg * 8 + r8;
        qa[r8] += xv * wq[r * 33 + c];
        ka[r8] += xv * wk[r * 33 + c];
        va[r8] += xv * wvs[r * 33 + c];
      }
    }
    int t = tbase + ch * 64 + tl;
#pragma unroll
    for (int r8 = 0; r8 < 8; r8++) {
      int r = rg * 8 + r8;
      size_t o = (size_t)a * 16384 + (size_t)r * 512 + t;
      Q[o] = qa[r8]; Kq[o] = ka[r8]; Vq[o] = va[r8];
    }
  }
}

// ---------------- A2: M = max_u(QK) - sum_u(QK)/512, then top-U indices per (a,h)
__global__ __launch_bounds__(512) void topk_k(const float* __restrict__ Q,
    const float* __restrict__ Kq, const int* __restrict__ idxs,
    int* __restrict__ Mtop, int U) {
  __shared__ float Ks[2048];
  __shared__ float Ml[512];
  __shared__ float rv[8];
  __shared__ int ri[8];
  int bh = blockIdx.x;
  int tid = threadIdx.x, lane = tid & 63, wv = tid >> 6;
  size_t base = (size_t)bh * 2048;
#pragma unroll
  for (int i = 0; i < 4; i++) Ks[i * 512 + tid] = Kq[base + i * 512 + tid];
  float q0 = Q[base + tid], q1 = Q[base + 512 + tid];
  float q2 = Q[base + 1024 + tid], q3 = Q[base + 1536 + tid];
  __syncthreads();
  float mx = NEG_INF, sm = 0.f;
  for (int u = 0; u < U; u++) {
    int it = idxs[tid * U + u];
    it = min(max(it, 0), 511);
    float s = q0 * Ks[it] + q1 * Ks[512 + it] + q2 * Ks[1024 + it] + q3 * Ks[1536 + it];
    mx = fmaxf(mx, s); sm += s;
  }
  Ml[tid] = mx - sm * (1.f / 512.f);
  __syncthreads();
  for (int s_i = 0; s_i < U; s_i++) {
    float v = Ml[tid]; int ii = tid;
#pragma unroll
    for (int off = 32; off; off >>= 1) {
      float ov = __shfl_xor(v, off); int oi = __shfl_xor(ii, off);
      if (ov > v || (ov == v && oi < ii)) { v = ov; ii = oi; }
    }
    if (lane == 0) { rv[wv] = v; ri[wv] = ii; }
    __syncthreads();
    if (tid == 0) {
      float bv = rv[0]; int bi = ri[0];
      for (int w = 1; w < 8; w++)
        if (rv[w] > bv || (rv[w] == bv && ri[w] < bi)) { bv = rv[w]; bi = ri[w]; }
      Mtop[bh * U + s_i] = bi;
      Ml[bi] = NEG_INF;
    }
    __syncthreads();
  }
}

// ---------------- A3: scores+softmax+upd, V-cumsum, scatter -> Ctx (aliases Q buffer)
__global__ __launch_bounds__(256) void attn_k(const float* __restrict__ Q,
    const float* __restrict__ Kq, const float* __restrict__ Vq,
    const int* __restrict__ Mtop, float* __restrict__ Ctx, int U) {
  __shared__ float Ks[2048];
  __shared__ float Vs[2048];
  __shared__ int mt[64];
  __shared__ float Qr[64][4];
  __shared__ float upd[64][4];
  int bh = blockIdx.x;
  int tid = threadIdx.x, lane = tid & 63, wv = tid >> 6;
  size_t base = (size_t)bh * 2048;
#pragma unroll
  for (int i = 0; i < 8; i++) {
    Ks[i * 256 + tid] = Kq[base + i * 256 + tid];
    Vs[i * 256 + tid] = Vq[base + i * 256 + tid];
  }
  if (tid < U) mt[tid] = Mtop[bh * U + tid];
  __syncthreads();
  if (tid < 4 * U) { int u = tid >> 2, d = tid & 3; Qr[u][d] = Q[base + d * 512 + mt[u]]; }
  __syncthreads();
  for (int u = wv; u < U; u += 4) {
    int mrow = mt[u];
    float q0 = Qr[u][0], q1 = Qr[u][1], q2 = Qr[u][2], q3 = Qr[u][3];
    float sv[8]; float lmax = NEG_INF;
#pragma unroll
    for (int jj = 0; jj < 8; jj++) {
      int k = jj * 64 + lane;
      float s = NEG_INF;
      if (k <= mrow)
        s = 0.5f * (q0 * Ks[k] + q1 * Ks[512 + k] + q2 * Ks[1024 + k] + q3 * Ks[1536 + k]);
      sv[jj] = s; lmax = fmaxf(lmax, s);
    }
#pragma unroll
    for (int off = 32; off; off >>= 1) lmax = fmaxf(lmax, __shfl_xor(lmax, off));
    float ls = 0.f, p0 = 0.f, p1 = 0.f, p2 = 0.f, p3 = 0.f;
#pragma unroll
    for (int jj = 0; jj < 8; jj++) {
      int k = jj * 64 + lane;
      if (k <= mrow) {
        float p = __expf(sv[jj] - lmax);
        ls += p; p0 += p * Vs[k]; p1 += p * Vs[512 + k];
        p2 += p * Vs[1024 + k]; p3 += p * Vs[1536 + k];
      }
    }
#pragma unroll
    for (int off = 32; off; off >>= 1) {
      ls += __shfl_xor(ls, off); p0 += __shfl_xor(p0, off); p1 += __shfl_xor(p1, off);
      p2 += __shfl_xor(p2, off); p3 += __shfl_xor(p3, off);
    }
    if (lane == 0) {
      float inv = 1.f / ls;
      upd[u][0] = p0 * inv; upd[u][1] = p1 * inv; upd[u][2] = p2 * inv; upd[u][3] = p3 * inv;
    }
  }
  __syncthreads();
  { // cumsum over t: wave wv owns d = wv
    float v[8];
    int b0 = wv * 512 + lane * 8;
#pragma unroll
    for (int q = 0; q < 8; q++) v[q] = Vs[b0 + q];
#pragma unroll
    for (int q = 1; q < 8; q++) v[q] += v[q - 1];
    float x = v[7];
    for (int off = 1; off < 64; off <<= 1) {
      float y = __shfl_up(x, off);
      if (lane >= off) x += y;
    }
    float excl = x - v[7];
#pragma unroll
    for (int q = 0; q < 8; q++) Vs[b0 + q] = v[q] + excl;
  }
  __syncthreads();
  if (tid < 4 * U) { int u = tid >> 2, d = tid & 3; Vs[d * 512 + mt[u]] = upd[u][d]; }
  __syncthreads();
#pragma unroll
  for (int i = 0; i < 8; i++) Ctx[base + i * 256 + tid] = Vs[i * 256 + tid];
}

// ---------------- A4: out-projection -> Y[a][t][r]
__global__ __launch_bounds__(256) void oproj_k(const float* __restrict__ Ctx,
    const float* __restrict__ Wo, const float* __restrict__ bo, float* __restrict__ Y) {
  __shared__ float cs[32 * 256];
  __shared__ float wo[32 * 33];
  __shared__ float bos[32];
  int tid = threadIdx.x;
  int a = blockIdx.x, t0 = blockIdx.y * 256;
#pragma unroll
  for (int i = 0; i < 4; i++) {
    int e = i * 256 + tid; int r = e >> 5, c = e & 31;
    wo[r * 33 + c] = Wo[e];
  }
  if (tid < 32) bos[tid] = bo[tid];
#pragma unroll
  for (int i = 0; i < 32; i++) {
    int e = i * 256 + tid; int row = e >> 8, col = e & 255;
    cs[e] = Ctx[(size_t)a * 16384 + (size_t)row * 512 + t0 + col];
  }
  __syncthreads();
  int rl = tid & 31, tw = tid >> 5;
  for (int ti = 0; ti < 32; ti++) {
    int t = ti * 8 + tw;
    float acc = bos[rl];
#pragma unroll
    for (int rp = 0; rp < 32; rp++) acc += cs[rp * 256 + t] * wo[rl * 33 + rp];
    Y[(size_t)a * 16384 + (size_t)(t0 + t) * 32 + rl] = acc;
  }
}

// ---------------- T1: transpose Y (128 x 16384) -> xh[m][a] with relu+res1+bn1, also f bf16
__global__ __launch_bounds__(256) void bn1t_k(const float* __restrict__ Y,
    const float* __restrict__ x, const float* __restrict__ g1, const float* __restrict__ be1,
    const float* __restrict__ me1, const float* __restrict__ va1,
    float* __restrict__ Xh, unsigned short* __restrict__ Fb) {
  __shared__ float tl[32][33];
  int tx = threadIdx.x & 31, ty = threadIdx.x >> 5;
  int c0 = blockIdx.x * 32;  // m index (0..16383)
  int r0 = blockIdx.y * 32;  // a index (0..127)
#pragma unroll
  for (int i = 0; i < 4; i++) {
    tl[ty + i * 8][tx] = Y[(size_t)(r0 + ty + i * 8) * 16384 + c0 + tx];
  }
  __syncthreads();
#pragma unroll
  for (int i = 0; i < 4; i++) {
    int m = c0 + ty + i * 8;
    int a = r0 + tx;
    float v = tl[tx][ty + i * 8];
    int ch = m & 31;
    size_t oi = (size_t)m * 128 + a;
    float val = fmaxf(v, 0.f) + x[oi];
    float s = g1[ch] * rsqrtf(va1[ch] + EPSF);
    float res = (val - me1[ch]) * s + be1[ch];
    Xh[oi] = res;
    Fb[oi] = f2bf(res);
  }
}

// ---------------- GEMM (B^T layout): C[m][n] = sum_k A[m][k]*Bw[n][k], A bf16, Bw fp32
// EPI 0: relu(acc+bias) -> bf16 Hout.  EPI 1: bn2(relu(acc+bias)+res2) -> fp32 Out.
template <int BM, int BN, int EPI>
__global__ __launch_bounds__(256, 2) void gemm_bt(
    const unsigned short* __restrict__ A, const float* __restrict__ Bw,
    const float* __restrict__ bias, int M, int N, int K,
    unsigned short* __restrict__ Hout, const float* __restrict__ res2,
    const float* __restrict__ g2, const float* __restrict__ be2,
    const float* __restrict__ me2, const float* __restrict__ va2,
    float* __restrict__ Out) {
  constexpr int MI = BM / 32;
  constexpr int NJ = BN / 32;
  __shared__ unsigned short As[BM * 32];
  __shared__ unsigned short Bs[BN * 32];
  int tid = threadIdx.x;
  int lane = tid & 63, wv = tid >> 6;
  int wm = wv >> 1, wn = wv & 1;
  int m0 = blockIdx.x * BM, n0 = blockIdx.y * BN;
  int frow = lane & 15;
  int fk = (lane >> 4) << 3;
  f32x4 acc[MI][NJ];
#pragma unroll
  for (int i = 0; i < MI; i++)
#pragma unroll
    for (int j = 0; j < NJ; j++) {
      f32x4 z = {0.f, 0.f, 0.f, 0.f};
      acc[i][j] = z;
    }
  constexpr int ITA = (BM * 64) / 4096;  // 16B chunks per thread for A tile
  for (int k0 = 0; k0 < K; k0 += 32) {
    __syncthreads();
#pragma unroll
    for (int i = 0; i < ITA; i++) {
      int e = i * 256 + tid;
      const unsigned short* gp = A + ((size_t)(m0 + (e >> 2)) * K + k0 + ((e & 3) << 3));
      async16(gp, (char*)As + i * 4096 + wv * 1024);
    }
#pragma unroll
    for (int i = 0; i < BN / 32; i++) {
      int e = i * 256 + tid;
      int row = e >> 3, kc = (e & 7) << 2;
      const float4 w = *(const float4*)(Bw + (size_t)(n0 + row) * K + k0 + kc);
      ushort4 pk;
      pk.x = f2bf(w.x); pk.y = f2bf(w.y); pk.z = f2bf(w.z); pk.w = f2bf(w.w);
      *(ushort4*)(Bs + e * 4) = pk;
    }
    __syncthreads();
    bf16x8 af[MI], bfr[NJ];
#pragma unroll
    for (int i = 0; i < MI; i++)
      af[i] = *(const bf16x8*)(As + (wm * (BM / 2) + i * 16 + frow) * 32 + fk);
#pragma unroll
    for (int j = 0; j < NJ; j++)
      bfr[j] = *(const bf16x8*)(Bs + (wn * (BN / 2) + j * 16 + frow) * 32 + fk);
#pragma unroll
    for (int i = 0; i < MI; i++)
#pragma unroll
      for (int j = 0; j < NJ; j++)
        acc[i][j] = __builtin_amdgcn_mfma_f32_16x16x32_bf16(af[i], bfr[j], acc[i][j], 0, 0, 0);
  }
#pragma unroll
  for (int i = 0; i < MI; i++)
#pragma unroll
    for (int j = 0; j < NJ; j++) {
      int n = n0 + wn * (BN / 2) + j * 16 + frow;
      int mb = m0 + wm * (BM / 2) + i * 16 + ((lane >> 4) << 2);
      float bb = bias[n];
      if constexpr (EPI == 0) {
#pragma unroll
        for (int r = 0; r < 4; r++) {
          float v = fmaxf(acc[i][j][r] + bb, 0.f);
          Hout[(size_t)(mb + r) * N + n] = f2bf(v);
        }
      } else {
        int ch = n >> 7;
        float s = g2[ch] * rsqrtf(va2[ch] + EPSF);
        float mu = me2[ch], bt = be2[ch];
#pragma unroll
        for (int r = 0; r < 4; r++) {
          float v = fmaxf(acc[i][j][r] + bb, 0.f);
          size_t oi = (size_t)(mb + r) * N + n;
          v += res2[oi];
          Out[oi] = (v - mu) * s + bt;
        }
      }
    }
}

extern "C" void kernel_launch(void* const* d_in, const int* in_sizes, int n_in,
                              void* d_out, int out_size, void* d_ws, size_t ws_size,
                              hipStream_t stream) {
  const float* x  = (const float*)d_in[0];
  const float* Wq = (const float*)d_in[1];  const float* bq = (const float*)d_in[2];
  const float* Wk = (const float*)d_in[3];  const float* bk = (const float*)d_in[4];
  const float* Wv = (const float*)d_in[5];  const float* bv = (const float*)d_in[6];
  const float* Wo = (const float*)d_in[7];  const float* bo = (const float*)d_in[8];
  const float* g1 = (const float*)d_in[9];  const float* be1 = (const float*)d_in[10];
  const float* me1 = (const float*)d_in[11]; const float* va1 = (const float*)d_in[12];
  const float* W1 = (const float*)d_in[13]; const float* b1 = (const float*)d_in[14];
  const float* W2 = (const float*)d_in[15]; const float* b2 = (const float*)d_in[16];
  const float* g2 = (const float*)d_in[17]; const float* be2 = (const float*)d_in[18];
  const float* me2 = (const float*)d_in[19]; const float* va2 = (const float*)d_in[20];
  const int* idxs = (const int*)d_in[21];
  int U = in_sizes[21] / 512;
  float* out = (float*)d_out;

  char* ws = (char*)d_ws;
  float* QC = (float*)(ws);                    // 8 MB: Q, then Ctx (alias, per-slice safe)
  float* Kb = (float*)(ws + (8u << 20));       // 8 MB: K, then h bf16 (alias)
  float* Vb = (float*)(ws + (16u << 20));      // 8 MB: V, then f bf16 (alias)
  float* YT = (float*)(ws + (24u << 20));      // 8 MB: xT, then Y (alias)
  float* Xh = (float*)(ws + (32u << 20));      // 8 MB: res2 fp32
  int* Mtop = (int*)(ws + (40u << 20));        // top-k indices
  unsigned short* Fb = (unsigned short*)Vb;    // f bf16 (512 x 4096)
  unsigned short* Hb = (unsigned short*)Kb;    // h bf16 (512 x 8192)

  dim3 b256(256);
  // T0: x (16384 x 128) -> xT (128 x 16384)
  transpose_k<<<dim3(4, 512), b256, 0, stream>>>(x, YT, 16384, 128);
  // A1: QKV projection -> Q/K/V [a][r][t]
  qkv_k<<<dim3(128, 2), b256, 0, stream>>>(YT, Wq, bq, Wk, bk, Wv, bv, QC, Kb, Vb);
  // A2: sparsity measure + top-U per (a,h)
  topk_k<<<dim3(1024), dim3(512), 0, stream>>>(QC, Kb, idxs, Mtop, U);
  // A3: attention core -> Ctx (aliases Q)
  attn_k<<<dim3(1024), b256, 0, stream>>>(QC, Kb, Vb, Mtop, QC, U);
  // A4: out-projection -> Y [a][t][r] (aliases xT)
  oproj_k<<<dim3(128, 2), b256, 0, stream>>>(QC, Wo, bo, YT);
  // T1: transpose + relu + res1 + bn1 -> Xh fp32 + f bf16
  bn1t_k<<<dim3(512, 4), b256, 0, stream>>>(YT, x, g1, be1, me1, va1, Xh, Fb);
  // G1: h = relu(f @ W1^T + b1), bf16
  gemm_bt<128, 128, 0><<<dim3(4, 64), b256, 0, stream>>>(
      Fb, W1, b1, 512, 8192, 4096, Hb, nullptr, nullptr, nullptr, nullptr, nullptr, nullptr);
  // G2: out = bn2(relu(h @ W2^T + b2) + Xh)
  gemm_bt<64, 128, 1><<<dim3(8, 32), b256, 0, stream>>>(
      Hb, W2, b2, 512, 4096, 8192, nullptr, Xh, g2, be2, me2, va2, out);
}

// Round 2
// 667.209 us; speedup vs baseline: 1.5708x; 1.5708x over previous
//
#include <hip/hip_runtime.h>
#include <stdint.h>

#define EPSF 1e-5f
#define NEG_INF (-1e30f)

typedef float f32x4 __attribute__((ext_vector_type(4)));
typedef __bf16 bf16x8 __attribute__((ext_vector_type(8)));
typedef unsigned short u16x8 __attribute__((ext_vector_type(8)));

typedef __attribute__((address_space(3))) unsigned char* as3_ptr;
typedef const __attribute__((address_space(1))) unsigned char* as1_ptr;

__device__ __forceinline__ void async16(const void* g, void* l) {
  __builtin_amdgcn_global_load_lds((as1_ptr)g, (as3_ptr)l, 16, 0, 0);
}

// waits: vmcnt<=N, lgkm/exp unconstrained
#define WAITVM(N) __builtin_amdgcn_s_waitcnt(0x0F70 | ((N) & 0xF) | ((((N) >> 4) & 3) << 14))

__device__ __forceinline__ unsigned short f2bf(float f) {
  union { float f; unsigned int u; } v; v.f = f;
  unsigned int r = v.u + 0x7FFFu + ((v.u >> 16) & 1u);
  return (unsigned short)(r >> 16);
}
__device__ __forceinline__ unsigned short f2bf_fast(float f) {
  union { float f; unsigned int u; } v; v.f = f;
  return (unsigned short)((v.u + 0x8000u) >> 16);
}

// ---------------- T0: generic 32x32 transpose
__global__ __launch_bounds__(256) void transpose_k(const float* __restrict__ src,
                                                   float* __restrict__ dst, int R, int C) {
  __shared__ float tl[32][33];
  int tx = threadIdx.x & 31, ty = threadIdx.x >> 5;
  int c0 = blockIdx.x * 32, r0 = blockIdx.y * 32;
#pragma unroll
  for (int i = 0; i < 4; i++)
    tl[ty + i * 8][tx] = src[(size_t)(r0 + ty + i * 8) * C + c0 + tx];
  __syncthreads();
#pragma unroll
  for (int i = 0; i < 4; i++)
    dst[(size_t)(c0 + ty + i * 8) * R + r0 + tx] = tl[tx][ty + i * 8];
}

// ---------------- A1: QKV projection
__global__ __launch_bounds__(256) void qkv_k(const float* __restrict__ xT,
    const float* __restrict__ Wq, const float* __restrict__ bq,
    const float* __restrict__ Wk, const float* __restrict__ bk,
    const float* __restrict__ Wv, const float* __restrict__ bv,
    float* __restrict__ Q, float* __restrict__ Kq, float* __restrict__ Vq) {
  __shared__ float xs[64 * 33];
  __shared__ float wq[32 * 33], wk[32 * 33], wvs[32 * 33];
  __shared__ float bqs[32], bks[32], bvs[32];
  int tid = threadIdx.x;
  int a = blockIdx.x;
  int tbase = blockIdx.y * 256;
#pragma unroll
  for (int i = 0; i < 4; i++) {
    int e = i * 256 + tid; int r = e >> 5, c = e & 31;
    wq[r * 33 + c] = Wq[e]; wk[r * 33 + c] = Wk[e]; wvs[r * 33 + c] = Wv[e];
  }
  if (tid < 32) { bqs[tid] = bq[tid]; bks[tid] = bk[tid]; bvs[tid] = bv[tid]; }
  int tl = tid & 63, rg = tid >> 6;
  for (int ch = 0; ch < 4; ch++) {
    __syncthreads();
#pragma unroll
    for (int i = 0; i < 8; i++) {
      int e = i * 256 + tid; int r = e >> 5, c = e & 31;
      xs[r * 33 + c] = xT[(size_t)a * 16384 + (size_t)(tbase + ch * 64) * 32 + e];
    }
    __syncthreads();
    float qa[8], ka[8], va[8];
#pragma unroll
    for (int r8 = 0; r8 < 8; r8++) {
      int r = rg * 8 + r8; qa[r8] = bqs[r]; ka[r8] = bks[r]; va[r8] = bvs[r];
    }
    for (int c = 0; c < 32; c++) {
      float xv = xs[tl * 33 + c];
#pragma unroll
      for (int r8 = 0; r8 < 8; r8++) {
        int r = rg * 8 + r8;
        qa[r8] += xv * wq[r * 33 + c];
        ka[r8] += xv * wk[r * 33 + c];
        va[r8] += xv * wvs[r * 33 + c];
      }
    }
    int t = tbase + ch * 64 + tl;
#pragma unroll
    for (int r8 = 0; r8 < 8; r8++) {
      int r = rg * 8 + r8;
      size_t o = (size_t)a * 16384 + (size_t)r * 512 + t;
      Q[o] = qa[r8]; Kq[o] = ka[r8]; Vq[o] = va[r8];
    }
  }
}

// ---------------- A2: top-U selection
__global__ __launch_bounds__(512) void topk_k(const float* __restrict__ Q,
    const float* __restrict__ Kq, const int* __restrict__ idxs,
    int* __restrict__ Mtop, int U) {
  __shared__ float Ks[2048];
  __shared__ float Ml[512];
  __shared__ float rv[8];
  __shared__ int ri[8];
  int bh = blockIdx.x;
  int tid = threadIdx.x, lane = tid & 63, wv = tid >> 6;
  size_t base = (size_t)bh * 2048;
#pragma unroll
  for (int i = 0; i < 4; i++) Ks[i * 512 + tid] = Kq[base + i * 512 + tid];
  float q0 = Q[base + tid], q1 = Q[base + 512 + tid];
  float q2 = Q[base + 1024 + tid], q3 = Q[base + 1536 + tid];
  __syncthreads();
  float mx = NEG_INF, sm = 0.f;
  for (int u = 0; u < U; u++) {
    int it = idxs[tid * U + u];
    it = min(max(it, 0), 511);
    float s = q0 * Ks[it] + q1 * Ks[512 + it] + q2 * Ks[1024 + it] + q3 * Ks[1536 + it];
    mx = fmaxf(mx, s); sm += s;
  }
  Ml[tid] = mx - sm * (1.f / 512.f);
  __syncthreads();
  for (int s_i = 0; s_i < U; s_i++) {
    float v = Ml[tid]; int ii = tid;
#pragma unroll
    for (int off = 32; off; off >>= 1) {
      float ov = __shfl_xor(v, off); int oi = __shfl_xor(ii, off);
      if (ov > v || (ov == v && oi < ii)) { v = ov; ii = oi; }
    }
    if (lane == 0) { rv[wv] = v; ri[wv] = ii; }
    __syncthreads();
    if (tid == 0) {
      float bv = rv[0]; int bi = ri[0];
      for (int w = 1; w < 8; w++)
        if (rv[w] > bv || (rv[w] == bv && ri[w] < bi)) { bv = rv[w]; bi = ri[w]; }
      Mtop[bh * U + s_i] = bi;
      Ml[bi] = NEG_INF;
    }
    __syncthreads();
  }
}

// ---------------- A3: attention core
__global__ __launch_bounds__(256) void attn_k(const float* __restrict__ Q,
    const float* __restrict__ Kq, const float* __restrict__ Vq,
    const int* __restrict__ Mtop, float* __restrict__ Ctx, int U) {
  __shared__ float Ks[2048];
  __shared__ float Vs[2048];
  __shared__ int mt[64];
  __shared__ float Qr[64][4];
  __shared__ float upd[64][4];
  int bh = blockIdx.x;
  int tid = threadIdx.x, lane = tid & 63, wv = tid >> 6;
  size_t base = (size_t)bh * 2048;
#pragma unroll
  for (int i = 0; i < 8; i++) {
    Ks[i * 256 + tid] = Kq[base + i * 256 + tid];
    Vs[i * 256 + tid] = Vq[base + i * 256 + tid];
  }
  if (tid < U) mt[tid] = Mtop[bh * U + tid];
  __syncthreads();
  if (tid < 4 * U) { int u = tid >> 2, d = tid & 3; Qr[u][d] = Q[base + d * 512 + mt[u]]; }
  __syncthreads();
  for (int u = wv; u < U; u += 4) {
    int mrow = mt[u];
    float q0 = Qr[u][0], q1 = Qr[u][1], q2 = Qr[u][2], q3 = Qr[u][3];
    float sv[8]; float lmax = NEG_INF;
#pragma unroll
    for (int jj = 0; jj < 8; jj++) {
      int k = jj * 64 + lane;
      float s = NEG_INF;
      if (k <= mrow)
        s = 0.5f * (q0 * Ks[k] + q1 * Ks[512 + k] + q2 * Ks[1024 + k] + q3 * Ks[1536 + k]);
      sv[jj] = s; lmax = fmaxf(lmax, s);
    }
#pragma unroll
    for (int off = 32; off; off >>= 1) lmax = fmaxf(lmax, __shfl_xor(lmax, off));
    float ls = 0.f, p0 = 0.f, p1 = 0.f, p2 = 0.f, p3 = 0.f;
#pragma unroll
    for (int jj = 0; jj < 8; jj++) {
      int k = jj * 64 + lane;
      if (k <= mrow) {
        float p = __expf(sv[jj] - lmax);
        ls += p; p0 += p * Vs[k]; p1 += p * Vs[512 + k];
        p2 += p * Vs[1024 + k]; p3 += p * Vs[1536 + k];
      }
    }
#pragma unroll
    for (int off = 32; off; off >>= 1) {
      ls += __shfl_xor(ls, off); p0 += __shfl_xor(p0, off); p1 += __shfl_xor(p1, off);
      p2 += __shfl_xor(p2, off); p3 += __shfl_xor(p3, off);
    }
    if (lane == 0) {
      float inv = 1.f / ls;
      upd[u][0] = p0 * inv; upd[u][1] = p1 * inv; upd[u][2] = p2 * inv; upd[u][3] = p3 * inv;
    }
  }
  __syncthreads();
  {
    float v[8];
    int b0 = wv * 512 + lane * 8;
#pragma unroll
    for (int q = 0; q < 8; q++) v[q] = Vs[b0 + q];
#pragma unroll
    for (int q = 1; q < 8; q++) v[q] += v[q - 1];
    float x = v[7];
    for (int off = 1; off < 64; off <<= 1) {
      float y = __shfl_up(x, off);
      if (lane >= off) x += y;
    }
    float excl = x - v[7];
#pragma unroll
    for (int q = 0; q < 8; q++) Vs[b0 + q] = v[q] + excl;
  }
  __syncthreads();
  if (tid < 4 * U) { int u = tid >> 2, d = tid & 3; Vs[d * 512 + mt[u]] = upd[u][d]; }
  __syncthreads();
#pragma unroll
  for (int i = 0; i < 8; i++) Ctx[base + i * 256 + tid] = Vs[i * 256 + tid];
}

// ---------------- A4: out-projection
__global__ __launch_bounds__(256) void oproj_k(const float* __restrict__ Ctx,
    const float* __restrict__ Wo, const float* __restrict__ bo, float* __restrict__ Y) {
  __shared__ float cs[32 * 256];
  __shared__ float wo[32 * 33];
  __shared__ float bos[32];
  int tid = threadIdx.x;
  int a = blockIdx.x, t0 = blockIdx.y * 256;
#pragma unroll
  for (int i = 0; i < 4; i++) {
    int e = i * 256 + tid; int r = e >> 5, c = e & 31;
    wo[r * 33 + c] = Wo[e];
  }
  if (tid < 32) bos[tid] = bo[tid];
#pragma unroll
  for (int i = 0; i < 32; i++) {
    int e = i * 256 + tid; int row = e >> 8, col = e & 255;
    cs[e] = Ctx[(size_t)a * 16384 + (size_t)row * 512 + t0 + col];
  }
  __syncthreads();
  int rl = tid & 31, tw = tid >> 5;
  for (int ti = 0; ti < 32; ti++) {
    int t = ti * 8 + tw;
    float acc = bos[rl];
#pragma unroll
    for (int rp = 0; rp < 32; rp++) acc += cs[rp * 256 + t] * wo[rl * 33 + rp];
    Y[(size_t)a * 16384 + (size_t)(t0 + t) * 32 + rl] = acc;
  }
}

// ---------------- T1: transpose + relu + res1 + bn1 -> Xh fp32 + f bf16
__global__ __launch_bounds__(256) void bn1t_k(const float* __restrict__ Y,
    const float* __restrict__ x, const float* __restrict__ g1, const float* __restrict__ be1,
    const float* __restrict__ me1, const float* __restrict__ va1,
    float* __restrict__ Xh, unsigned short* __restrict__ Fb) {
  __shared__ float tl[32][33];
  int tx = threadIdx.x & 31, ty = threadIdx.x >> 5;
  int c0 = blockIdx.x * 32;
  int r0 = blockIdx.y * 32;
#pragma unroll
  for (int i = 0; i < 4; i++)
    tl[ty + i * 8][tx] = Y[(size_t)(r0 + ty + i * 8) * 16384 + c0 + tx];
  __syncthreads();
#pragma unroll
  for (int i = 0; i < 4; i++) {
    int m = c0 + ty + i * 8;
    int a = r0 + tx;
    float v = tl[tx][ty + i * 8];
    int ch = m & 31;
    size_t oi = (size_t)m * 128 + a;
    float val = fmaxf(v, 0.f) + x[oi];
    float s = g1[ch] * rsqrtf(va1[ch] + EPSF);
    float res = (val - me1[ch]) * s + be1[ch];
    Xh[oi] = res;
    Fb[oi] = f2bf(res);
  }
}

// ---------------- Pipelined GEMM: C[m][n] = sum_k A[m][k] * Bw[n][k]
// A bf16 [M][K]; Bw fp32 [N][K] staged raw via global_load_lds, cvt at frag read.
// 3-stage pipeline, raw s_barrier + explicit vmcnt. XOR bank swizzle in LDS.
// EPI 0: relu(acc+bias) -> bf16 Hout.  EPI 1: bn2(relu(acc+bias)+res2) -> fp32 Out.
template <int BM, int BN, int EPI>
__global__ __launch_bounds__(256) void gemm_pipe(
    const unsigned short* __restrict__ A, const float* __restrict__ Bw,
    const float* __restrict__ bias, int K, int N, int gridN,
    unsigned short* __restrict__ Hout, const float* __restrict__ res2,
    const float* __restrict__ g2, const float* __restrict__ be2,
    const float* __restrict__ me2, const float* __restrict__ va2,
    float* __restrict__ Out) {
  constexpr int BK = 32;
  constexpr int ABYTES = BM * BK * 2;
  constexpr int BBYTES = BN * BK * 4;
  constexpr int STGB = ABYTES + BBYTES;
  constexpr int SA = ABYTES / 4096;  // async16 per thread, A
  constexpr int SB = BBYTES / 4096;  // async16 per thread, B
  constexpr int S = SA + SB;
  constexpr int MI = BM / 32;
  constexpr int NJ = BN / 32;
  __shared__ unsigned char lds[3 * STGB];

  int tid = threadIdx.x;
  int lane = tid & 63, wv = tid >> 6;
  int wm = wv >> 1, wn = wv & 1;
  // XCD-aware swizzle: 4 m-tile siblings (same n-tile) -> same XCD, adjacent slots
  int lin = blockIdx.x;
  int xcd = lin & 7, l = lin >> 3;
  int mt = l & 3;
  int nt = xcd * (gridN >> 3) + (l >> 2);
  int m0 = mt * BM, n0 = nt * BN;

  int frow = lane & 15;
  int q = lane >> 4;

  f32x4 acc[MI][NJ];
#pragma unroll
  for (int i = 0; i < MI; i++)
#pragma unroll
    for (int j = 0; j < NJ; j++) { f32x4 z = {0.f, 0.f, 0.f, 0.f}; acc[i][j] = z; }

  int nk = K >> 5;

  auto issue_stage = [&](int ks, int stg) {
    unsigned char* sb = lds + stg * STGB;
#pragma unroll
    for (int i = 0; i < SA; i++) {
      int e = i * 256 + tid;
      int row = e >> 2;
      int g = (e & 3) ^ ((row >> 1) & 3);
      async16(A + (size_t)(m0 + row) * K + ks + g * 8, sb + i * 4096 + wv * 1024);
    }
#pragma unroll
    for (int i = 0; i < SB; i++) {
      int e = i * 256 + tid;
      int row = e >> 3;
      int g = (e & 7) ^ (row & 7);
      async16(Bw + (size_t)(n0 + row) * K + ks + g * 4, sb + ABYTES + i * 4096 + wv * 1024);
    }
  };

  issue_stage(0, 0);
  if (nk > 1) issue_stage(32, 1);

  for (int k = 0; k < nk; k++) {
    if (k + 1 < nk) { WAITVM(S); } else { WAITVM(0); }
    __builtin_amdgcn_s_barrier();
    unsigned char* bufA = lds + (k % 3) * STGB;
    unsigned char* bufB = bufA + ABYTES;
    bf16x8 af[MI];
    bf16x8 bfr[NJ];
#pragma unroll
    for (int i = 0; i < MI; i++) {
      int row = wm * (BM / 2) + i * 16 + frow;
      af[i] = *(const bf16x8*)(bufA + row * 64 + ((q ^ ((row >> 1) & 3)) << 4));
    }
#pragma unroll
    for (int j = 0; j < NJ; j++) {
      int row = wn * (BN / 2) + j * 16 + frow;
      const unsigned char* rb = bufB + row * 128;
      int sw = row & 7;
      float4 w0 = *(const float4*)(rb + (((2 * q + 0) ^ sw) << 4));
      float4 w1 = *(const float4*)(rb + (((2 * q + 1) ^ sw) << 4));
      union { u16x8 u; bf16x8 b; } cv;
      cv.u[0] = f2bf_fast(w0.x); cv.u[1] = f2bf_fast(w0.y);
      cv.u[2] = f2bf_fast(w0.z); cv.u[3] = f2bf_fast(w0.w);
      cv.u[4] = f2bf_fast(w1.x); cv.u[5] = f2bf_fast(w1.y);
      cv.u[6] = f2bf_fast(w1.z); cv.u[7] = f2bf_fast(w1.w);
      bfr[j] = cv.b;
    }
    if (k + 2 < nk) issue_stage((k + 2) * 32, (k + 2) % 3);
#pragma unroll
    for (int i = 0; i < MI; i++)
#pragma unroll
      for (int j = 0; j < NJ; j++)
        acc[i][j] = __builtin_amdgcn_mfma_f32_16x16x32_bf16(af[i], bfr[j], acc[i][j], 0, 0, 0);
  }

#pragma unroll
  for (int i = 0; i < MI; i++)
#pragma unroll
    for (int j = 0; j < NJ; j++) {
      int n = n0 + wn * (BN / 2) + j * 16 + frow;
      int mb = m0 + wm * (BM / 2) + i * 16 + (q << 2);
      float bb = bias[n];
      if constexpr (EPI == 0) {
#pragma unroll
        for (int r = 0; r < 4; r++) {
          float v = fmaxf(acc[i][j][r] + bb, 0.f);
          Hout[(size_t)(mb + r) * N + n] = f2bf(v);
        }
      } else {
        int ch = n >> 7;
        float s = g2[ch] * rsqrtf(va2[ch] + EPSF);
        float mu = me2[ch], bt = be2[ch];
#pragma unroll
        for (int r = 0; r < 4; r++) {
          float v = fmaxf(acc[i][j][r] + bb, 0.f);
          size_t oi = (size_t)(mb + r) * N + n;
          v += res2[oi];
          Out[oi] = (v - mu) * s + bt;
        }
      }
    }
}

extern "C" void kernel_launch(void* const* d_in, const int* in_sizes, int n_in,
                              void* d_out, int out_size, void* d_ws, size_t ws_size,
                              hipStream_t stream) {
  const float* x  = (const float*)d_in[0];
  const float* Wq = (const float*)d_in[1];  const float* bq = (const float*)d_in[2];
  const float* Wk = (const float*)d_in[3];  const float* bk = (const float*)d_in[4];
  const float* Wv = (const float*)d_in[5];  const float* bv = (const float*)d_in[6];
  const float* Wo = (const float*)d_in[7];  const float* bo = (const float*)d_in[8];
  const float* g1 = (const float*)d_in[9];  const float* be1 = (const float*)d_in[10];
  const float* me1 = (const float*)d_in[11]; const float* va1 = (const float*)d_in[12];
  const float* W1 = (const float*)d_in[13]; const float* b1 = (const float*)d_in[14];
  const float* W2 = (const float*)d_in[15]; const float* b2 = (const float*)d_in[16];
  const float* g2 = (const float*)d_in[17]; const float* be2 = (const float*)d_in[18];
  const float* me2 = (const float*)d_in[19]; const float* va2 = (const float*)d_in[20];
  const int* idxs = (const int*)d_in[21];
  int U = in_sizes[21] / 512;
  float* out = (float*)d_out;

  char* ws = (char*)d_ws;
  float* QC = (float*)(ws);                    // 8 MB: Q, then Ctx
  float* Kb = (float*)(ws + (8u << 20));       // 8 MB: K, then h bf16
  float* Vb = (float*)(ws + (16u << 20));      // 8 MB: V, then f bf16
  float* YT = (float*)(ws + (24u << 20));      // 8 MB: xT, then Y
  float* Xh = (float*)(ws + (32u << 20));      // 8 MB: res2 fp32
  int* Mtop = (int*)(ws + (40u << 20));
  unsigned short* Fb = (unsigned short*)Vb;
  unsigned short* Hb = (unsigned short*)Kb;

  dim3 b256(256);
  transpose_k<<<dim3(4, 512), b256, 0, stream>>>(x, YT, 16384, 128);
  qkv_k<<<dim3(128, 2), b256, 0, stream>>>(YT, Wq, bq, Wk, bk, Wv, bv, QC, Kb, Vb);
  topk_k<<<dim3(1024), dim3(512), 0, stream>>>(QC, Kb, idxs, Mtop, U);
  attn_k<<<dim3(1024), b256, 0, stream>>>(QC, Kb, Vb, Mtop, QC, U);
  oproj_k<<<dim3(128, 2), b256, 0, stream>>>(QC, Wo, bo, YT);
  bn1t_k<<<dim3(512, 4), b256, 0, stream>>>(YT, x, g1, be1, me1, va1, Xh, Fb);
  // G1: h = relu(f @ W1^T + b1) -> bf16 [512][8192]
  gemm_pipe<128, 128, 0><<<dim3(256), b256, 0, stream>>>(
      Fb, W1, b1, 4096, 8192, 64, Hb, nullptr, nullptr, nullptr, nullptr, nullptr, nullptr);
  // G2: out = bn2(relu(h @ W2^T + b2) + Xh) -> fp32 [512][4096]
  gemm_pipe<128, 64, 1><<<dim3(256), b256, 0, stream>>>(
      Hb, W2, b2, 8192, 4096, 64, nullptr, Xh, g2, be2, me2, va2, out);
}